// Round 5
// baseline (33.525 us; speedup 1.0000x reference)
//
#include <hip/hip_runtime.h>

// Problem constants (from the reference file)
#define GN_NODES   1000000
#define GN_TPB     1024
#define GN_NBLOCKS 256
#define GN_T       (GN_TPB * GN_NBLOCKS)   // 262144 threads total

// Fully-linear network: out = sum_b f_beta(S_b), where S_b are block-partial
// input sums and beta carries the bias terms (1e6 on block 0 only, 0 elsewhere).
// Each block contributes ONE float atomicAdd to out[0] (zeroed by memset).
// Weights are staged into LDS at kernel START so the per-block epilogue has
// no exposed global-latency tail.

// LDS weight-buffer layout (floats):
//  WC1@0(30) BC1@30(10) WC2@40(100) BC2@140(10) WN1@150(20) BN1@170(10)
//  WN2@180(100) BN2@280(10) WCB@290(200) BCB@490(10) WDE@500(10) BDE@510(1)

__global__ __launch_bounds__(GN_TPB) void gn_fused(
    const float* __restrict__ cart,
    const float* __restrict__ neigh,
    const float* __restrict__ Wc1,  const float* __restrict__ bc1,
    const float* __restrict__ Wc2,  const float* __restrict__ bc2,
    const float* __restrict__ Wn1,  const float* __restrict__ bn1,
    const float* __restrict__ Wn2,  const float* __restrict__ bn2,
    const float* __restrict__ Wcomb, const float* __restrict__ bcomb,
    const float* __restrict__ Wdeco, const float* __restrict__ bdeco,
    const int* __restrict__ kptr,
    float* __restrict__ out)
{
    __shared__ float wbuf[512];
    __shared__ float red[5][GN_TPB / 64];
    __shared__ int   kk_sh;

    const int t   = threadIdx.x;
    const int tid = blockIdx.x * GN_TPB + t;

    // ---- Stage weights into LDS (one element per thread; latency hides
    // under the streaming loop below; ordered by the __syncthreads later).
    if      (t <  30) wbuf[t] = Wc1[t];
    else if (t <  40) wbuf[t] = bc1[t - 30];
    else if (t < 140) wbuf[t] = Wc2[t - 40];
    else if (t < 150) wbuf[t] = bc2[t - 140];
    else if (t < 170) wbuf[t] = Wn1[t - 150];
    else if (t < 180) wbuf[t] = bn1[t - 170];
    else if (t < 280) wbuf[t] = Wn2[t - 180];
    else if (t < 290) wbuf[t] = bn2[t - 280];
    else if (t < 490) wbuf[t] = Wcomb[t - 290];
    else if (t < 500) wbuf[t] = bcomb[t - 490];
    else if (t < 510) wbuf[t] = Wdeco[t - 500];
    else if (t == 510) wbuf[t] = bdeco[0];
    else if (t == 511) kk_sh = *kptr;

    // ---- Streaming reduction.
    float sx = 0.f, sy = 0.f, sz = 0.f, s0 = 0.f, s1 = 0.f;

    // cart: 3,000,000 floats = 250,000 chunks of 12 floats (4 nodes).
    // Component pattern within a chunk: x y z x y z x y z x y z.
    const float4* cart4 = reinterpret_cast<const float4*>(cart);
    for (int c = tid; c < 250000; c += GN_T) {
        float4 a = cart4[3 * c + 0];
        float4 b = cart4[3 * c + 1];
        float4 d = cart4[3 * c + 2];
        sx += a.x + a.w + b.z + d.y;
        sy += a.y + b.x + b.w + d.z;
        sz += a.z + b.y + d.x + d.w;
    }

    // neigh: 8,000,000 floats = 2,000,000 float4; components alternate 0,1.
    const float4* n4 = reinterpret_cast<const float4*>(neigh);
    int i = tid;
    for (; i + GN_T < 2000000; i += 2 * GN_T) {
        float4 v = n4[i];
        float4 w = n4[i + GN_T];
        s0 += (v.x + v.z) + (w.x + w.z);
        s1 += (v.y + v.w) + (w.y + w.w);
    }
    if (i < 2000000) {
        float4 v = n4[i];
        s0 += v.x + v.z;
        s1 += v.y + v.w;
    }

    // Wave (64-lane) reduce.
    for (int o = 32; o > 0; o >>= 1) {
        sx += __shfl_down(sx, o);
        sy += __shfl_down(sy, o);
        sz += __shfl_down(sz, o);
        s0 += __shfl_down(s0, o);
        s1 += __shfl_down(s1, o);
    }

    const int wave = t >> 6;
    if ((t & 63) == 0) {
        red[0][wave] = sx; red[1][wave] = sy; red[2][wave] = sz;
        red[3][wave] = s0; red[4][wave] = s1;
    }
    __syncthreads();   // orders red[] stores AND the wbuf staging

    if (t == 0) {
        float Sc0 = 0.f, Sc1 = 0.f, Sc2 = 0.f, Sn0 = 0.f, Sn1 = 0.f;
        #pragma unroll
        for (int w = 0; w < GN_TPB / 64; ++w) {
            Sc0 += red[0][w]; Sc1 += red[1][w]; Sc2 += red[2][w];
            Sn0 += red[3][w]; Sn1 += red[4][w];
        }

        // Bias factor: block 0 carries all NODES*bias terms; others are pure
        // linear. Sum over blocks == reference result (everything is affine).
        const float isb0 = (blockIdx.x == 0) ? 1.f : 0.f;
        const float beta = isb0 * 1.0e6f;

        const float* WC1 = wbuf +   0; const float* BC1 = wbuf +  30;
        const float* WC2 = wbuf +  40; const float* BC2 = wbuf + 140;
        const float* WN1 = wbuf + 150; const float* BN1 = wbuf + 170;
        const float* WN2 = wbuf + 180; const float* BN2 = wbuf + 280;
        const float* WCB = wbuf + 290; const float* BCB = wbuf + 490;
        const float* WDE = wbuf + 500; const float  BDE = wbuf[510];

        // H_b = (Sc_b @ Wc1^T + beta*bc1) @ Wc2^T + beta*bc2
        float tt[10], H[10];
        #pragma unroll
        for (int p = 0; p < 10; ++p)
            tt[p] = WC1[p*3+0]*Sc0 + WC1[p*3+1]*Sc1 + WC1[p*3+2]*Sc2
                  + beta * BC1[p];
        #pragma unroll
        for (int q = 0; q < 10; ++q) {
            float s = beta * BC2[q];
            #pragma unroll
            for (int p = 0; p < 10; ++p) s += WC2[q*10+p] * tt[p];
            H[q] = s;
        }

        // Mv_b = (0.25*Sn_b @ Wn1^T + beta*bn1) @ Wn2^T + beta*bn2
        float u[10], Mv[10];
        #pragma unroll
        for (int p = 0; p < 10; ++p)
            u[p] = WN1[p*2+0]*(Sn0*0.25f) + WN1[p*2+1]*(Sn1*0.25f)
                 + beta * BN1[p];
        #pragma unroll
        for (int q = 0; q < 10; ++q) {
            float s = beta * BN2[q];
            #pragma unroll
            for (int p = 0; p < 10; ++p) s += WN2[q*10+p] * u[p];
            Mv[q] = s;
        }

        // k comb rounds on the block-partial state.
        const int kk = kk_sh;
        float S[10], C[10];
        #pragma unroll
        for (int q = 0; q < 10; ++q) S[q] = H[q];
        for (int it = 0; it < kk; ++it) {
            #pragma unroll
            for (int q = 0; q < 10; ++q) {
                float s = beta * BCB[q];
                #pragma unroll
                for (int p = 0; p < 10; ++p) {
                    s += WCB[q*20 + p]      * Mv[p];
                    s += WCB[q*20 + 10 + p] * S[p];
                }
                C[q] = s;
            }
            #pragma unroll
            for (int q = 0; q < 10; ++q) S[q] = C[q];
        }

        // decode; bdeco only once (block 0).
        float o = isb0 * BDE;
        #pragma unroll
        for (int q = 0; q < 10; ++q) o += WDE[q] * S[q];

        atomicAdd(out, o);   // one RMW per block, 256 total, staggered
    }
}

extern "C" void kernel_launch(void* const* d_in, const int* in_sizes, int n_in,
                              void* d_out, int out_size, void* d_ws, size_t ws_size,
                              hipStream_t stream) {
    const float* cart  = (const float*)d_in[0];
    const float* neigh = (const float*)d_in[1];
    const float* Wc1   = (const float*)d_in[2];
    const float* bc1   = (const float*)d_in[3];
    const float* Wc2   = (const float*)d_in[4];
    const float* bc2   = (const float*)d_in[5];
    const float* Wn1   = (const float*)d_in[6];
    const float* bn1   = (const float*)d_in[7];
    const float* Wn2   = (const float*)d_in[8];
    const float* bn2   = (const float*)d_in[9];
    const float* Wcomb = (const float*)d_in[10];
    const float* bcomb = (const float*)d_in[11];
    const float* Wdeco = (const float*)d_in[12];
    const float* bdeco = (const float*)d_in[13];
    const int*   kptr  = (const int*)d_in[14];

    // Zero the single output accumulator (deterministic start each call).
    hipMemsetAsync(d_out, 0, sizeof(float), stream);

    gn_fused<<<GN_NBLOCKS, GN_TPB, 0, stream>>>(
        cart, neigh,
        Wc1, bc1, Wc2, bc2, Wn1, bn1, Wn2, bn2,
        Wcomb, bcomb, Wdeco, bdeco, kptr,
        (float*)d_out);
}

// Round 6
// 30.277 us; speedup vs baseline: 1.1073x; 1.1073x over previous
//
#include <hip/hip_runtime.h>

// Problem constants (from the reference file)
#define GN_NODES   1000000
#define GN_TPB     1024
#define GN_NBLOCKS 512
#define GN_T       (GN_TPB * GN_NBLOCKS)   // 524288 threads total

// Fully-linear network: out = sum_b f_beta(S_b), where S_b are block-partial
// input sums and beta carries the bias terms (1e6 on block 0 only, 0 elsewhere).
// Each block contributes ONE float atomicAdd to out[0] (zeroed by memset).
//
// Load structure: every thread issues ALL its loads (<=7 float4) as
// independent registers before any dependent arithmetic -> single vmcnt
// wait, maximal memory-level parallelism. 8 waves/SIMD (VGPR<=64).
//   neigh: 2,000,000 float4 = 3*T + 427136  -> 3 loads + 1 conditional
//   cart : 250,000 triples of float4        -> 3 loads if tid < 250000

__global__ __launch_bounds__(GN_TPB) void gn_fused(
    const float* __restrict__ cart,
    const float* __restrict__ neigh,
    const float* __restrict__ Wc1,  const float* __restrict__ bc1,
    const float* __restrict__ Wc2,  const float* __restrict__ bc2,
    const float* __restrict__ Wn1,  const float* __restrict__ bn1,
    const float* __restrict__ Wn2,  const float* __restrict__ bn2,
    const float* __restrict__ Wcomb, const float* __restrict__ bcomb,
    const float* __restrict__ Wdeco, const float* __restrict__ bdeco,
    const int* __restrict__ kptr,
    float* __restrict__ out)
{
    const int t   = threadIdx.x;
    const int tid = blockIdx.x * GN_TPB + t;

    // ---- Issue all neigh loads up front (independent registers).
    const float4* n4 = reinterpret_cast<const float4*>(neigh);
    float4 n0 = n4[tid];
    float4 n1 = n4[tid + GN_T];
    float4 n2 = n4[tid + 2 * GN_T];
    float4 n3 = make_float4(0.f, 0.f, 0.f, 0.f);
    if (tid < 2000000 - 3 * GN_T)          // 427136
        n3 = n4[tid + 3 * GN_T];

    // ---- cart: one 12-float chunk (4 nodes) for tid < 250000.
    // Component pattern within a chunk: x y z x y z x y z x y z.
    float sx = 0.f, sy = 0.f, sz = 0.f;
    const float4* cart4 = reinterpret_cast<const float4*>(cart);
    if (tid < 250000) {
        float4 a = cart4[3 * tid + 0];
        float4 b = cart4[3 * tid + 1];
        float4 d = cart4[3 * tid + 2];
        sx = a.x + a.w + b.z + d.y;
        sy = a.y + b.x + b.w + d.z;
        sz = a.z + b.y + d.x + d.w;
    }

    // neigh components alternate 0,1,0,1 inside each float4.
    float s0 = (n0.x + n0.z) + (n1.x + n1.z) + (n2.x + n2.z) + (n3.x + n3.z);
    float s1 = (n0.y + n0.w) + (n1.y + n1.w) + (n2.y + n2.w) + (n3.y + n3.w);

    // ---- Wave (64-lane) reduce.
    for (int o = 32; o > 0; o >>= 1) {
        sx += __shfl_down(sx, o);
        sy += __shfl_down(sy, o);
        sz += __shfl_down(sz, o);
        s0 += __shfl_down(s0, o);
        s1 += __shfl_down(s1, o);
    }

    __shared__ float red[5][GN_TPB / 64];
    const int wave = t >> 6;
    if ((t & 63) == 0) {
        red[0][wave] = sx; red[1][wave] = sy; red[2][wave] = sz;
        red[3][wave] = s0; red[4][wave] = s1;
    }
    __syncthreads();

    if (t == 0) {
        float Sc0 = 0.f, Sc1 = 0.f, Sc2 = 0.f, Sn0 = 0.f, Sn1 = 0.f;
        #pragma unroll
        for (int w = 0; w < GN_TPB / 64; ++w) {
            Sc0 += red[0][w]; Sc1 += red[1][w]; Sc2 += red[2][w];
            Sn0 += red[3][w]; Sn1 += red[4][w];
        }

        // Bias factor: block 0 carries all NODES*bias terms; others are pure
        // linear. Sum over blocks == reference result (everything is affine).
        const float isb0 = (blockIdx.x == 0) ? 1.f : 0.f;
        const float beta = isb0 * 1.0e6f;

        // H_b = (Sc_b @ Wc1^T + beta*bc1) @ Wc2^T + beta*bc2
        float tt[10], H[10];
        #pragma unroll
        for (int p = 0; p < 10; ++p)
            tt[p] = Wc1[p*3+0]*Sc0 + Wc1[p*3+1]*Sc1 + Wc1[p*3+2]*Sc2
                  + beta * bc1[p];
        #pragma unroll
        for (int q = 0; q < 10; ++q) {
            float s = beta * bc2[q];
            #pragma unroll
            for (int p = 0; p < 10; ++p) s += Wc2[q*10+p] * tt[p];
            H[q] = s;
        }

        // Mv_b = (0.25*Sn_b @ Wn1^T + beta*bn1) @ Wn2^T + beta*bn2
        float u[10], Mv[10];
        #pragma unroll
        for (int p = 0; p < 10; ++p)
            u[p] = Wn1[p*2+0]*(Sn0*0.25f) + Wn1[p*2+1]*(Sn1*0.25f)
                 + beta * bn1[p];
        #pragma unroll
        for (int q = 0; q < 10; ++q) {
            float s = beta * bn2[q];
            #pragma unroll
            for (int p = 0; p < 10; ++p) s += Wn2[q*10+p] * u[p];
            Mv[q] = s;
        }

        // k comb rounds on the block-partial state.
        const int kk = *kptr;
        float S[10], C[10];
        #pragma unroll
        for (int q = 0; q < 10; ++q) S[q] = H[q];
        for (int it = 0; it < kk; ++it) {
            #pragma unroll
            for (int q = 0; q < 10; ++q) {
                float s = beta * bcomb[q];
                #pragma unroll
                for (int p = 0; p < 10; ++p) {
                    s += Wcomb[q*20 + p]      * Mv[p];
                    s += Wcomb[q*20 + 10 + p] * S[p];
                }
                C[q] = s;
            }
            #pragma unroll
            for (int q = 0; q < 10; ++q) S[q] = C[q];
        }

        // decode; bdeco only once (block 0).
        float o = isb0 * bdeco[0];
        #pragma unroll
        for (int q = 0; q < 10; ++q) o += Wdeco[q] * S[q];

        atomicAdd(out, o);   // one RMW per block, 512 total, staggered
    }
}

extern "C" void kernel_launch(void* const* d_in, const int* in_sizes, int n_in,
                              void* d_out, int out_size, void* d_ws, size_t ws_size,
                              hipStream_t stream) {
    const float* cart  = (const float*)d_in[0];
    const float* neigh = (const float*)d_in[1];
    const float* Wc1   = (const float*)d_in[2];
    const float* bc1   = (const float*)d_in[3];
    const float* Wc2   = (const float*)d_in[4];
    const float* bc2   = (const float*)d_in[5];
    const float* Wn1   = (const float*)d_in[6];
    const float* bn1   = (const float*)d_in[7];
    const float* Wn2   = (const float*)d_in[8];
    const float* bn2   = (const float*)d_in[9];
    const float* Wcomb = (const float*)d_in[10];
    const float* bcomb = (const float*)d_in[11];
    const float* Wdeco = (const float*)d_in[12];
    const float* bdeco = (const float*)d_in[13];
    const int*   kptr  = (const int*)d_in[14];

    // Zero the single output accumulator (deterministic start each call).
    hipMemsetAsync(d_out, 0, sizeof(float), stream);

    gn_fused<<<GN_NBLOCKS, GN_TPB, 0, stream>>>(
        cart, neigh,
        Wc1, bc1, Wc2, bc2, Wn1, bn1, Wn2, bn2,
        Wcomb, bcomb, Wdeco, bdeco, kptr,
        (float*)d_out);
}

// Round 7
// 21.009 us; speedup vs baseline: 1.5957x; 1.4412x over previous
//
#include <hip/hip_runtime.h>

// Problem constants (from the reference file)
#define GN_NODES   1000000
#define GN_TPB     1024
#define GN_NBLOCKS 256
#define GN_T       (GN_TPB * GN_NBLOCKS)   // 262144 threads total

// Fully-linear network: out = sum_b f_beta(S_b), where S_b are block-partial
// input sums and beta carries the bias terms (1e6 on block 0 only, 0 elsewhere).
// Each block contributes ONE float atomicAdd to out[0] (zeroed by memset).
//
// Epilogue is WAVE-PARALLEL (lane q owns component q of each 10-wide layer;
// weights load 10 lanes per instruction; cross-lane operands via __shfl) --
// replaces the previous ~460 serial scalar weight loads per block.

__global__ __launch_bounds__(GN_TPB) void gn_fused(
    const float* __restrict__ cart,
    const float* __restrict__ neigh,
    const float* __restrict__ Wc1,  const float* __restrict__ bc1,
    const float* __restrict__ Wc2,  const float* __restrict__ bc2,
    const float* __restrict__ Wn1,  const float* __restrict__ bn1,
    const float* __restrict__ Wn2,  const float* __restrict__ bn2,
    const float* __restrict__ Wcomb, const float* __restrict__ bcomb,
    const float* __restrict__ Wdeco, const float* __restrict__ bdeco,
    const int* __restrict__ kptr,
    float* __restrict__ out)
{
    const int t   = threadIdx.x;
    const int tid = blockIdx.x * GN_TPB + t;

    float sx = 0.f, sy = 0.f, sz = 0.f, s0 = 0.f, s1 = 0.f;

    // ---- Streaming reduction (identical to the best-measured R4 loop). ----
    // cart: 3,000,000 floats = 250,000 chunks of 12 floats (4 nodes).
    // Component pattern within a chunk: x y z x y z x y z x y z.
    const float4* cart4 = reinterpret_cast<const float4*>(cart);
    for (int c = tid; c < 250000; c += GN_T) {
        float4 a = cart4[3 * c + 0];
        float4 b = cart4[3 * c + 1];
        float4 d = cart4[3 * c + 2];
        sx += a.x + a.w + b.z + d.y;
        sy += a.y + b.x + b.w + d.z;
        sz += a.z + b.y + d.x + d.w;
    }

    // neigh: 8,000,000 floats = 2,000,000 float4; components alternate 0,1.
    const float4* n4 = reinterpret_cast<const float4*>(neigh);
    int i = tid;
    for (; i + GN_T < 2000000; i += 2 * GN_T) {
        float4 v = n4[i];
        float4 w = n4[i + GN_T];
        s0 += (v.x + v.z) + (w.x + w.z);
        s1 += (v.y + v.w) + (w.y + w.w);
    }
    if (i < 2000000) {
        float4 v = n4[i];
        s0 += v.x + v.z;
        s1 += v.y + v.w;
    }

    // Wave (64-lane) reduce.
    for (int o = 32; o > 0; o >>= 1) {
        sx += __shfl_down(sx, o);
        sy += __shfl_down(sy, o);
        sz += __shfl_down(sz, o);
        s0 += __shfl_down(s0, o);
        s1 += __shfl_down(s1, o);
    }

    __shared__ float red[5][GN_TPB / 64];
    const int wave = t >> 6;
    if ((t & 63) == 0) {
        red[0][wave] = sx; red[1][wave] = sy; red[2][wave] = sz;
        red[3][wave] = s0; red[4][wave] = s1;
    }
    __syncthreads();

    // ---- Wave-parallel epilogue: wave 0 only. ----
    if (t < 64) {
        const int q  = t;                    // lane id
        const int ql = (q < 10) ? q : 0;     // clamped index for safe loads

        // Block totals: lane w in [0,16) reads red[c][w], 4-step xor-reduce.
        const int lw = q & 15;
        float Sc0 = red[0][lw], Sc1 = red[1][lw], Sc2 = red[2][lw];
        float Sn0 = red[3][lw], Sn1 = red[4][lw];
        #pragma unroll
        for (int o = 8; o > 0; o >>= 1) {
            Sc0 += __shfl_xor(Sc0, o);
            Sc1 += __shfl_xor(Sc1, o);
            Sc2 += __shfl_xor(Sc2, o);
            Sn0 += __shfl_xor(Sn0, o);
            Sn1 += __shfl_xor(Sn1, o);
        }

        // Bias factor: block 0 carries all NODES*bias terms; others are pure
        // linear. Sum over blocks == reference result (everything is affine).
        const float isb0 = (blockIdx.x == 0) ? 1.f : 0.f;
        const float beta = isb0 * 1.0e6f;

        // tt[q] = Wc1[q,:]*Sc + beta*bc1[q]   (lane q holds tt)
        float tt = Wc1[ql*3+0]*Sc0 + Wc1[ql*3+1]*Sc1 + Wc1[ql*3+2]*Sc2
                 + beta * bc1[ql];
        // H[q] = beta*bc2[q] + sum_p Wc2[q,p] * tt[p]
        float H = beta * bc2[ql];
        #pragma unroll
        for (int p = 0; p < 10; ++p)
            H += Wc2[ql*10+p] * __shfl(tt, p);

        // u[q] = Wn1[q,:]*(Sn/4) + beta*bn1[q]
        float u = Wn1[ql*2+0]*(Sn0*0.25f) + Wn1[ql*2+1]*(Sn1*0.25f)
                + beta * bn1[ql];
        // Mv[q] = beta*bn2[q] + sum_p Wn2[q,p] * u[p]
        float Mv = beta * bn2[ql];
        #pragma unroll
        for (int p = 0; p < 10; ++p)
            Mv += Wn2[ql*10+p] * __shfl(u, p);

        // k comb rounds on the block-partial state (lane q holds S[q]).
        const int kk = *kptr;
        float S = H;
        for (int it = 0; it < kk; ++it) {
            float C = beta * bcomb[ql];
            #pragma unroll
            for (int p = 0; p < 10; ++p) {
                C += Wcomb[ql*20 + p]      * __shfl(Mv, p);
                C += Wcomb[ql*20 + 10 + p] * __shfl(S,  p);
            }
            S = C;
        }

        // decode on lane 0: o = isb0*bdeco + sum_q Wdeco[q]*S[q]
        float o = isb0 * bdeco[0];
        #pragma unroll
        for (int p = 0; p < 10; ++p)
            o += Wdeco[p] * __shfl(S, p);

        if (q == 0)
            atomicAdd(out, o);   // one RMW per block, 256 total, staggered
    }
}

extern "C" void kernel_launch(void* const* d_in, const int* in_sizes, int n_in,
                              void* d_out, int out_size, void* d_ws, size_t ws_size,
                              hipStream_t stream) {
    const float* cart  = (const float*)d_in[0];
    const float* neigh = (const float*)d_in[1];
    const float* Wc1   = (const float*)d_in[2];
    const float* bc1   = (const float*)d_in[3];
    const float* Wc2   = (const float*)d_in[4];
    const float* bc2   = (const float*)d_in[5];
    const float* Wn1   = (const float*)d_in[6];
    const float* bn1   = (const float*)d_in[7];
    const float* Wn2   = (const float*)d_in[8];
    const float* bn2   = (const float*)d_in[9];
    const float* Wcomb = (const float*)d_in[10];
    const float* bcomb = (const float*)d_in[11];
    const float* Wdeco = (const float*)d_in[12];
    const float* bdeco = (const float*)d_in[13];
    const int*   kptr  = (const int*)d_in[14];

    // Zero the single output accumulator (deterministic start each call).
    hipMemsetAsync(d_out, 0, sizeof(float), stream);

    gn_fused<<<GN_NBLOCKS, GN_TPB, 0, stream>>>(
        cart, neigh,
        Wc1, bc1, Wc2, bc2, Wn1, bn1, Wn2, bn2,
        Wcomb, bcomb, Wdeco, bdeco, kptr,
        (float*)d_out);
}